// Round 4
// baseline (216.347 us; speedup 1.0000x reference)
//
#include <hip/hip_runtime.h>

typedef unsigned short u16;
typedef __bf16 bf16x8 __attribute__((ext_vector_type(8)));
typedef float f32x4 __attribute__((ext_vector_type(4)));
typedef u16 u16x4 __attribute__((ext_vector_type(4)));
typedef u16 u16x8 __attribute__((ext_vector_type(8)));

#define LSEQ 2048
#define EMB  1024
#define NH   16
#define HDIM 64

// Q pre-scale: 1/sqrt(64) * log2(e)  (softmax computed in base 2)
#define QSCALE 0.1803368808f

#if __has_builtin(__builtin_amdgcn_exp2f)
#define EXP2(x) __builtin_amdgcn_exp2f(x)
#else
#define EXP2(x) __expf((x) * 0.6931471805599453f)
#endif

// native RTNE f32->bf16 (compiler emits v_cvt_pk_bf16_f32; do NOT hand-roll)
__device__ __forceinline__ u16 cvt_bf(float f) {
  __bf16 h = (__bf16)f;
  return __builtin_bit_cast(u16, h);
}
__device__ __forceinline__ float bf2f(u16 v) {
  return __uint_as_float(((unsigned)v) << 16);
}
__device__ __forceinline__ void async16(void* lds, const void* g) {
  __builtin_amdgcn_global_load_lds((const __attribute__((address_space(1))) void*)g,
                                   (__attribute__((address_space(3))) void*)lds, 16, 0, 0);
}
__device__ __forceinline__ f32x4 mfma16(bf16x8 a, bf16x8 b, f32x4 c) {
  return __builtin_amdgcn_mfma_f32_16x16x32_bf16(a, b, c, 0, 0, 0);
}

// ---------------- conversion kernels ----------------

__global__ void f32_to_bf16_vec(const float* __restrict__ in, u16* __restrict__ out, int n4) {
  int i = blockIdx.x * 256 + threadIdx.x;
  if (i < n4) {
    float4 v = ((const float4*)in)[i];
    u16x4 o = { cvt_bf(v.x), cvt_bf(v.y), cvt_bf(v.z), cvt_bf(v.w) };
    ((u16x4*)out)[i] = o;
  }
}

// in: fp32 [Kd][Nd] row-major -> out: bf16 [Nd][Kd] row-major (i.e. W^T)
__global__ void transpose_f32_bf16(const float* __restrict__ in, u16* __restrict__ out,
                                   int Kd, int Nd) {
  __shared__ float tile[32][33];
  int n0 = blockIdx.x * 32, k0 = blockIdx.y * 32;
  int tx = threadIdx.x, ty = threadIdx.y;  // block (32,8)
#pragma unroll
  for (int i = 0; i < 4; ++i)
    tile[ty + i * 8][tx] = in[(size_t)(k0 + ty + i * 8) * Nd + n0 + tx];
  __syncthreads();
#pragma unroll
  for (int i = 0; i < 4; ++i)
    out[(size_t)(n0 + ty + i * 8) * Kd + k0 + tx] = cvt_bf(tile[tx][ty + i * 8]);
}

// ---------------- GEMM (A [M,K] bf16 row-major, Bt [N,K] bf16 row-major) ----------------
// 3-buffer, 2-deep prefetch pipeline: counted s_waitcnt vmcnt(4) + raw s_barrier
// per K-step (prefetch loads stay in flight across barriers; vmcnt(0) only on
// the final step). LDS 48KB -> 3 blocks/CU.
// MODE 0: QKV epilogue (bias add, per-head scatter; Q scaled by QSCALE, V transposed)
// MODE 1: fp32 out + bias
template<int NCOLS, int MODE>
__launch_bounds__(256)
__global__ void gemm_bt(const u16* __restrict__ A, const u16* __restrict__ Bt,
                        const float* __restrict__ bias, float* __restrict__ Out,
                        u16* __restrict__ Qo, u16* __restrict__ Ko, u16* __restrict__ Vo) {
  __shared__ __attribute__((aligned(16))) u16 As[3][128 * 32];
  __shared__ __attribute__((aligned(16))) u16 Bs[3][128 * 32];
  const int tid = threadIdx.x;
  const int w = tid >> 6, l = tid & 63;
  const int g = l >> 4, cc = l & 15;
  // XCD-bijective swizzle (nwg % 8 == 0)
  constexpr int GX = NCOLS / 128;
  constexpr int CPX = GX * 32 / 8;
  const int orig = blockIdx.y * GX + blockIdx.x;
  const int wgid = (orig & 7) * CPX + (orig >> 3);
  const int m0 = (wgid / GX) * 128, n0 = (wgid % GX) * 128;
  const int wm = w >> 1, wn = w & 1;
  const int K = 1024;
  const int srow = w * 16 + (l >> 2);   // staging row (+ chunk*64)
  const int scol = (l & 3) * 8;         // staging col (elements)
  const u16* Ag = A + (size_t)(m0 + srow) * K + scol;
  const u16* Bg = Bt + (size_t)(n0 + srow) * K + scol;
  f32x4 acc[4][4] = {};

  auto stage = [&](int buf, int k0) {
    async16(&As[buf][w * 512], Ag + k0);
    async16(&As[buf][2048 + w * 512], Ag + (size_t)64 * K + k0);
    async16(&Bs[buf][w * 512], Bg + k0);
    async16(&Bs[buf][2048 + w * 512], Bg + (size_t)64 * K + k0);
  };

  stage(0, 0);
  stage(1, 32);
  int buf = 0;
  for (int k0 = 0; k0 < K; k0 += 32) {
    // wait for this step's stage (leave the newest 4 loads in flight)
    if (k0 + 32 < K) asm volatile("s_waitcnt vmcnt(4)" ::: "memory");
    else             asm volatile("s_waitcnt vmcnt(0)" ::: "memory");
    __builtin_amdgcn_s_barrier();
    __builtin_amdgcn_sched_barrier(0);
    if (k0 + 64 < K) {
      int nb = buf + 2; if (nb >= 3) nb -= 3;
      stage(nb, k0 + 64);
    }
    bf16x8 af[4], bfr[4];
#pragma unroll
    for (int mf = 0; mf < 4; ++mf)
      af[mf] = *(const bf16x8*)&As[buf][(wm * 64 + mf * 16 + cc) * 32 + g * 8];
#pragma unroll
    for (int nf = 0; nf < 4; ++nf)
      bfr[nf] = *(const bf16x8*)&Bs[buf][(wn * 64 + nf * 16 + cc) * 32 + g * 8];
#pragma unroll
    for (int mf = 0; mf < 4; ++mf)
#pragma unroll
      for (int nf = 0; nf < 4; ++nf)
        acc[mf][nf] = mfma16(af[mf], bfr[nf], acc[mf][nf]);
    if (++buf == 3) buf = 0;
  }

  // epilogue: C row = m0+wm*64+mf*16+g*4+r, col = n0+wn*64+nf*16+cc
#pragma unroll
  for (int mf = 0; mf < 4; ++mf) {
#pragma unroll
    for (int nf = 0; nf < 4; ++nf) {
      int n = n0 + wn * 64 + nf * 16 + cc;
      float bv = bias[n];
#pragma unroll
      for (int r = 0; r < 4; ++r) {
        int m = m0 + wm * 64 + mf * 16 + g * 4 + r;
        float val = acc[mf][nf][r] + bv;
        if (MODE == 0) {
          int bb = m >> 11, ls = m & (LSEQ - 1);
          int hd = n / 192;
          int rem = n - hd * 192;
          int which = rem >> 6, d = rem & 63;
          int bh = bb * NH + hd;
          if (which == 0)
            Qo[((size_t)bh * LSEQ + ls) * HDIM + d] = cvt_bf(val * QSCALE);
          else if (which == 1)
            Ko[((size_t)bh * LSEQ + ls) * HDIM + d] = cvt_bf(val);
          else
            Vo[((size_t)bh * HDIM + d) * LSEQ + ls] = cvt_bf(val);
        } else {
          Out[(size_t)m * NCOLS + n] = val;
        }
      }
    }
  }
}

// ---------------- flash attention ----------------
// Q,K: bf16 [B*H, L, D] (Q pre-scaled by QSCALE -> softmax in base 2);
// Vt: bf16 [B*H, D, L]; Y: bf16 [B, L, H*D]. Causal; rows >= mask_len fixed by
// meanv_fill. NO K/V LDS staging: KV is L2-resident (512KB/bh, 4 bh/XCD), MFMA
// fragments are read directly from global (16 rows x 64B per instr). Zero
// barriers; waves fully independent. LDS = per-wave P buffer only (8KB).
__launch_bounds__(256)
__global__ void attn_fwd(const u16* __restrict__ Q, const u16* __restrict__ Kb,
                         const u16* __restrict__ Vt, u16* __restrict__ Y) {
  __shared__ __attribute__((aligned(16))) u16 Ps[4 * 16 * 64];
  const int tid = threadIdx.x;
  const int w = tid >> 6, l = tid & 63;
  const int g = l >> 4, cc = l & 15;

  const int i = blockIdx.x;
  const int bh = i & 31;                 // XCD = i%8 -> 4 bh per XCD L2
  const int k = i >> 5, grp = k >> 3, j = k & 7;
  int qblk;
  if (grp == 0) qblk = 31 - j;
  else if (grp == 1) qblk = j;
  else if (grp == 2) qblk = 23 - j;
  else qblk = 8 + j;
  const int q0 = qblk * 64;
  const int nt = qblk + 1;

  char* Pw = (char*)&Ps[w * 16 * 64];
  const int xc = (cc & 7) << 4;
  const int b = bh >> 4, h = bh & (NH - 1);

  const u16* Qg = Q + ((size_t)bh * LSEQ + q0 + w * 16) * HDIM;
  bf16x8 qf0 = *(const bf16x8*)&Qg[cc * HDIM + g * 8];
  bf16x8 qf1 = *(const bf16x8*)&Qg[cc * HDIM + 32 + g * 8];

  bf16x8 onesf;
#pragma unroll
  for (int z = 0; z < 8; ++z) onesf[z] = (__bf16)1.0f;

  const u16* Kbh = Kb + (size_t)bh * LSEQ * HDIM;
  const u16* Vbh = Vt + (size_t)bh * HDIM * LSEQ;

  f32x4 o[4] = {};
  f32x4 ls = {};
  float mrow[4];
#pragma unroll
  for (int r = 0; r < 4; ++r) mrow[r] = -3e38f;

  for (int t = 0; t < nt; ++t) {
    const int kv0 = t * 64;
    const u16* Kt = Kbh + (size_t)kv0 * HDIM;
    const u16* Vc = Vbh + kv0;

    // S = Q K^T (base-2 scaled); fragments straight from L2
    f32x4 sf[4] = {};
    __builtin_amdgcn_s_setprio(1);
#pragma unroll
    for (int nf = 0; nf < 4; ++nf) {
      bf16x8 kf0 = *(const bf16x8*)&Kt[(nf * 16 + cc) * HDIM + g * 8];
      bf16x8 kf1 = *(const bf16x8*)&Kt[(nf * 16 + cc) * HDIM + 32 + g * 8];
      sf[nf] = mfma16(qf0, kf0, sf[nf]);
      sf[nf] = mfma16(qf1, kf1, sf[nf]);
    }
    __builtin_amdgcn_s_setprio(0);

    // issue V loads now; their latency hides under the softmax VALU phase
    bf16x8 vf[8];
#pragma unroll
    for (int nf = 0; nf < 4; ++nf) {
      vf[2 * nf]     = *(const bf16x8*)&Vc[(size_t)(nf * 16 + cc) * LSEQ + g * 8];
      vf[2 * nf + 1] = *(const bf16x8*)&Vc[(size_t)(nf * 16 + cc) * LSEQ + 32 + g * 8];
    }

    if (t == nt - 1) {  // diagonal tile: causal mask
#pragma unroll
      for (int nf = 0; nf < 4; ++nf) {
        int kvl = nf * 16 + cc;
#pragma unroll
        for (int r = 0; r < 4; ++r)
          if (kvl > w * 16 + g * 4 + r) sf[nf][r] = -1e30f;
      }
    }

    // tile max per row (4 shfl hops over the 16 lanes of group g)
    float tm[4];
#pragma unroll
    for (int r = 0; r < 4; ++r) {
      float m2 = fmaxf(fmaxf(sf[0][r], sf[1][r]), fmaxf(sf[2][r], sf[3][r]));
      m2 = fmaxf(m2, __shfl_xor(m2, 1));
      m2 = fmaxf(m2, __shfl_xor(m2, 2));
      m2 = fmaxf(m2, __shfl_xor(m2, 4));
      m2 = fmaxf(m2, __shfl_xor(m2, 8));
      tm[r] = m2;
    }
    // defer-rescale (T13): only rescale when max grew by > 8 (base-2)
    float dmax = fmaxf(fmaxf(tm[0] - mrow[0], tm[1] - mrow[1]),
                       fmaxf(tm[2] - mrow[2], tm[3] - mrow[3]));
    if (__any(dmax > 8.f)) {
#pragma unroll
      for (int r = 0; r < 4; ++r) {
        float mnew = fmaxf(mrow[r], tm[r]);
        float sc = EXP2(mrow[r] - mnew);
        mrow[r] = mnew;
        ls[r] *= sc;
#pragma unroll
        for (int nf = 0; nf < 4; ++nf) o[nf][r] *= sc;
      }
    }

    // P = exp2(S - m), write to per-wave LDS (swizzled); same-wave dep
#pragma unroll
    for (int r = 0; r < 4; ++r) {
      int q = g * 4 + r;
      int xr = (q & 7) << 4;
#pragma unroll
      for (int nf = 0; nf < 4; ++nf) {
        float pv = EXP2(sf[nf][r] - mrow[r]);
        *(u16*)(Pw + q * 128 + (((nf * 16 + cc) * 2) ^ xr)) = cvt_bf(pv);
      }
    }
    asm volatile("s_waitcnt lgkmcnt(0)" ::: "memory");
    __builtin_amdgcn_sched_barrier(0);

    bf16x8 pf0 = *(const bf16x8*)(Pw + cc * 128 + ((g * 16) ^ xc));
    bf16x8 pf1 = *(const bf16x8*)(Pw + cc * 128 + ((64 + g * 16) ^ xc));
    __builtin_amdgcn_s_setprio(1);
    // row-sum of P via MFMA against all-ones (replaces shfl-add reduce)
    ls = mfma16(pf1, onesf, mfma16(pf0, onesf, ls));
#pragma unroll
    for (int nf = 0; nf < 4; ++nf) {
      o[nf] = mfma16(pf0, vf[2 * nf], o[nf]);
      o[nf] = mfma16(pf1, vf[2 * nf + 1], o[nf]);
    }
    __builtin_amdgcn_s_setprio(0);
  }

  // epilogue: Y[b, q, h*64 + d]
#pragma unroll
  for (int r = 0; r < 4; ++r) {
    float inv = 1.0f / ls[r];
    int row = q0 + w * 16 + g * 4 + r;
    size_t base = ((size_t)b * LSEQ + row) * EMB + h * HDIM;
#pragma unroll
    for (int nf = 0; nf < 4; ++nf)
      Y[base + nf * 16 + cc] = cvt_bf(o[nf][r] * inv);
  }
}

// ---------------- mean-V fixup for rows >= mask_len ----------------
__global__ void meanv_fill(const u16* __restrict__ Vt, const int* __restrict__ mask_len,
                           u16* __restrict__ Y) {
  __shared__ float partial[256];
  __shared__ u16 mv[HDIM];
  int bh = blockIdx.x, b = bh >> 4, h = bh & (NH - 1);
  int tid = threadIdx.x;
  int d = tid >> 2, part = tid & 3;
  const u16* src = Vt + ((size_t)bh * HDIM + d) * LSEQ + part * 512;
  float s = 0.f;
  for (int i = 0; i < 512; i += 8) {
    u16x8 v = *(const u16x8*)&src[i];
#pragma unroll
    for (int j = 0; j < 8; ++j) s += bf2f(v[j]);
  }
  partial[tid] = s;
  __syncthreads();
  if (part == 0) {
    float t = partial[tid] + partial[tid + 1] + partial[tid + 2] + partial[tid + 3];
    mv[d] = cvt_bf(t * (1.0f / (float)LSEQ));
  }
  __syncthreads();
  int lo = mask_len[b];
  if (lo < 0) lo = 0;
  if (lo > LSEQ) lo = LSEQ;
  int total = (LSEQ - lo) * HDIM;
  for (int idx = tid; idx < total; idx += 256) {
    int row = lo + (idx >> 6), dd = idx & 63;
    Y[((size_t)b * LSEQ + row) * EMB + h * HDIM + dd] = mv[dd];
  }
}

// ---------------- launch ----------------
extern "C" void kernel_launch(void* const* d_in, const int* in_sizes, int n_in,
                              void* d_out, int out_size, void* d_ws, size_t ws_size,
                              hipStream_t stream) {
  (void)in_sizes; (void)n_in; (void)out_size; (void)ws_size;
  const float* x    = (const float*)d_in[0];
  const float* Wqkv = (const float*)d_in[1];
  const float* bqkv = (const float*)d_in[2];
  const float* Wo   = (const float*)d_in[3];
  const float* bo   = (const float*)d_in[4];
  const int* mask_len = (const int*)d_in[5];
  float* out = (float*)d_out;

  u16* ws = (u16*)d_ws;
  u16* xb    = ws;                              // 4M elems (x bf16) — reused as Y later
  u16* wqkvt = ws + (size_t)4 * 1024 * 1024;    // 3M (W_qkv^T bf16)
  u16* wot   = wqkvt + (size_t)3 * 1024 * 1024; // 1M (W_o^T bf16)
  u16* Qb    = wot + (size_t)1024 * 1024;       // 4M
  u16* Kb    = Qb + (size_t)4 * 1024 * 1024;    // 4M
  u16* Vtb   = Kb + (size_t)4 * 1024 * 1024;    // 4M
  u16* Yb    = xb;                              // alias: x dead after gemm_qkv

  f32_to_bf16_vec<<<4096, 256, 0, stream>>>(x, xb, 1024 * 1024);
  dim3 tb(32, 8);
  transpose_f32_bf16<<<dim3(96, 32), tb, 0, stream>>>(Wqkv, wqkvt, 1024, 3072);
  transpose_f32_bf16<<<dim3(32, 32), tb, 0, stream>>>(Wo, wot, 1024, 1024);
  gemm_bt<3072, 0><<<dim3(24, 32), 256, 0, stream>>>(xb, wqkvt, bqkv, nullptr, Qb, Kb, Vtb);
  attn_fwd<<<1024, 256, 0, stream>>>(Qb, Kb, Vtb, Yb);
  meanv_fill<<<32, 256, 0, stream>>>(Vtb, mask_len, Yb);
  gemm_bt<1024, 1><<<dim3(8, 32), 256, 0, stream>>>(Yb, wot, bo, out, nullptr, nullptr, nullptr);
}

// Round 5
// 147.321 us; speedup vs baseline: 1.4685x; 1.4685x over previous
//
#include <hip/hip_runtime.h>

typedef unsigned short u16;
typedef __bf16 bf16x8 __attribute__((ext_vector_type(8)));
typedef float f32x4 __attribute__((ext_vector_type(4)));
typedef u16 u16x4 __attribute__((ext_vector_type(4)));
typedef u16 u16x8 __attribute__((ext_vector_type(8)));

#define LSEQ 2048
#define EMB  1024
#define NH   16
#define HDIM 64

// Q pre-scale: 1/sqrt(64) * log2(e)  (softmax computed in base 2)
#define QSCALE 0.1803368808f

#if __has_builtin(__builtin_amdgcn_exp2f)
#define EXP2(x) __builtin_amdgcn_exp2f(x)
#else
#define EXP2(x) __expf((x) * 0.6931471805599453f)
#endif

// native RTNE f32->bf16 (compiler emits v_cvt_pk_bf16_f32; do NOT hand-roll)
__device__ __forceinline__ u16 cvt_bf(float f) {
  __bf16 h = (__bf16)f;
  return __builtin_bit_cast(u16, h);
}
__device__ __forceinline__ float bf2f(u16 v) {
  return __uint_as_float(((unsigned)v) << 16);
}
__device__ __forceinline__ void async16(void* lds, const void* g) {
  __builtin_amdgcn_global_load_lds((const __attribute__((address_space(1))) void*)g,
                                   (__attribute__((address_space(3))) void*)lds, 16, 0, 0);
}
__device__ __forceinline__ f32x4 mfma16(bf16x8 a, bf16x8 b, f32x4 c) {
  return __builtin_amdgcn_mfma_f32_16x16x32_bf16(a, b, c, 0, 0, 0);
}

// ---------------- conversion kernels ----------------

__global__ void f32_to_bf16_vec(const float* __restrict__ in, u16* __restrict__ out, int n4) {
  int i = blockIdx.x * 256 + threadIdx.x;
  if (i < n4) {
    float4 v = ((const float4*)in)[i];
    u16x4 o = { cvt_bf(v.x), cvt_bf(v.y), cvt_bf(v.z), cvt_bf(v.w) };
    ((u16x4*)out)[i] = o;
  }
}

// in: fp32 [Kd][Nd] row-major -> out: bf16 [Nd][Kd] row-major (i.e. W^T)
__global__ void transpose_f32_bf16(const float* __restrict__ in, u16* __restrict__ out,
                                   int Kd, int Nd) {
  __shared__ float tile[32][33];
  int n0 = blockIdx.x * 32, k0 = blockIdx.y * 32;
  int tx = threadIdx.x, ty = threadIdx.y;  // block (32,8)
#pragma unroll
  for (int i = 0; i < 4; ++i)
    tile[ty + i * 8][tx] = in[(size_t)(k0 + ty + i * 8) * Nd + n0 + tx];
  __syncthreads();
#pragma unroll
  for (int i = 0; i < 4; ++i)
    out[(size_t)(n0 + ty + i * 8) * Kd + k0 + tx] = cvt_bf(tile[tx][ty + i * 8]);
}

// ---------------- GEMM (A [M,K] bf16 row-major, Bt [N,K] bf16 row-major) ----------------
// 3-buffer, 2-deep prefetch pipeline: counted s_waitcnt vmcnt(4) + raw s_barrier
// per K-step (prefetch loads stay in flight across barriers; vmcnt(0) only on
// the final step). LDS 48KB -> 3 blocks/CU.  [R4: neutral vs R3 dbuf; keep]
// MODE 0: QKV epilogue (bias add, per-head scatter; Q scaled by QSCALE, V transposed)
// MODE 1: fp32 out + bias
template<int NCOLS, int MODE>
__launch_bounds__(256)
__global__ void gemm_bt(const u16* __restrict__ A, const u16* __restrict__ Bt,
                        const float* __restrict__ bias, float* __restrict__ Out,
                        u16* __restrict__ Qo, u16* __restrict__ Ko, u16* __restrict__ Vo) {
  __shared__ __attribute__((aligned(16))) u16 As[3][128 * 32];
  __shared__ __attribute__((aligned(16))) u16 Bs[3][128 * 32];
  const int tid = threadIdx.x;
  const int w = tid >> 6, l = tid & 63;
  const int g = l >> 4, cc = l & 15;
  // XCD-bijective swizzle (nwg % 8 == 0)
  constexpr int GX = NCOLS / 128;
  constexpr int CPX = GX * 32 / 8;
  const int orig = blockIdx.y * GX + blockIdx.x;
  const int wgid = (orig & 7) * CPX + (orig >> 3);
  const int m0 = (wgid / GX) * 128, n0 = (wgid % GX) * 128;
  const int wm = w >> 1, wn = w & 1;
  const int K = 1024;
  const int srow = w * 16 + (l >> 2);   // staging row (+ chunk*64)
  const int scol = (l & 3) * 8;         // staging col (elements)
  const u16* Ag = A + (size_t)(m0 + srow) * K + scol;
  const u16* Bg = Bt + (size_t)(n0 + srow) * K + scol;
  f32x4 acc[4][4] = {};

  auto stage = [&](int buf, int k0) {
    async16(&As[buf][w * 512], Ag + k0);
    async16(&As[buf][2048 + w * 512], Ag + (size_t)64 * K + k0);
    async16(&Bs[buf][w * 512], Bg + k0);
    async16(&Bs[buf][2048 + w * 512], Bg + (size_t)64 * K + k0);
  };

  stage(0, 0);
  stage(1, 32);
  int buf = 0;
  for (int k0 = 0; k0 < K; k0 += 32) {
    // wait for this step's stage (leave the newest 4 loads in flight)
    if (k0 + 32 < K) asm volatile("s_waitcnt vmcnt(4)" ::: "memory");
    else             asm volatile("s_waitcnt vmcnt(0)" ::: "memory");
    __builtin_amdgcn_s_barrier();
    __builtin_amdgcn_sched_barrier(0);
    if (k0 + 64 < K) {
      int nb = buf + 2; if (nb >= 3) nb -= 3;
      stage(nb, k0 + 64);
    }
    bf16x8 af[4], bfr[4];
#pragma unroll
    for (int mf = 0; mf < 4; ++mf)
      af[mf] = *(const bf16x8*)&As[buf][(wm * 64 + mf * 16 + cc) * 32 + g * 8];
#pragma unroll
    for (int nf = 0; nf < 4; ++nf)
      bfr[nf] = *(const bf16x8*)&Bs[buf][(wn * 64 + nf * 16 + cc) * 32 + g * 8];
#pragma unroll
    for (int mf = 0; mf < 4; ++mf)
#pragma unroll
      for (int nf = 0; nf < 4; ++nf)
        acc[mf][nf] = mfma16(af[mf], bfr[nf], acc[mf][nf]);
    if (++buf == 3) buf = 0;
  }

  // epilogue: C row = m0+wm*64+mf*16+g*4+r, col = n0+wn*64+nf*16+cc
#pragma unroll
  for (int mf = 0; mf < 4; ++mf) {
#pragma unroll
    for (int nf = 0; nf < 4; ++nf) {
      int n = n0 + wn * 64 + nf * 16 + cc;
      float bv = bias[n];
#pragma unroll
      for (int r = 0; r < 4; ++r) {
        int m = m0 + wm * 64 + mf * 16 + g * 4 + r;
        float val = acc[mf][nf][r] + bv;
        if (MODE == 0) {
          int bb = m >> 11, ls = m & (LSEQ - 1);
          int hd = n / 192;
          int rem = n - hd * 192;
          int which = rem >> 6, d = rem & 63;
          int bh = bb * NH + hd;
          if (which == 0)
            Qo[((size_t)bh * LSEQ + ls) * HDIM + d] = cvt_bf(val * QSCALE);
          else if (which == 1)
            Ko[((size_t)bh * LSEQ + ls) * HDIM + d] = cvt_bf(val);
          else
            Vo[((size_t)bh * HDIM + d) * LSEQ + ls] = cvt_bf(val);
        } else {
          Out[(size_t)m * NCOLS + n] = val;
        }
      }
    }
  }
}

// ---------------- flash attention ----------------
// Q,K: bf16 [B*H, L, D] (Q pre-scaled by QSCALE -> softmax in base 2);
// Vt: bf16 [B*H, D, L]; Y: bf16 [B, L, H*D]. Causal; rows >= mask_len fixed by
// meanv_fill.
// R5: LDS-staged K/V (R4's direct-L2 fragment reads were scatter-latency-bound),
// double-buffered with COUNTED vmcnt(4) + raw s_barrier (no vmcnt(0) drain in
// the loop -- prefetch stays in flight across barriers). 4 blocks/CU (40KB LDS).
__launch_bounds__(256)
__global__ void attn_fwd(const u16* __restrict__ Q, const u16* __restrict__ Kb,
                         const u16* __restrict__ Vt, u16* __restrict__ Y) {
  __shared__ __attribute__((aligned(16))) u16 Ks[2][64 * 64];
  __shared__ __attribute__((aligned(16))) u16 Vs[2][64 * 64];
  __shared__ __attribute__((aligned(16))) u16 Ps[4 * 16 * 64];
  const int tid = threadIdx.x;
  const int w = tid >> 6, l = tid & 63;
  const int g = l >> 4, cc = l & 15;

  const int i = blockIdx.x;
  const int bh = i & 31;                 // XCD = i%8 -> 4 bh per XCD L2
  const int k = i >> 5, grp = k >> 3, j = k & 7;
  int qblk;
  if (grp == 0) qblk = 31 - j;
  else if (grp == 1) qblk = j;
  else if (grp == 2) qblk = 23 - j;
  else qblk = 8 + j;
  const int q0 = qblk * 64;
  const int nt = qblk + 1;

  const int sr = w * 8 + (l >> 3);   // staging row (+ chunk*32)
  const int pb = (l & 7) * 16;       // physical byte within 128B row
  char* Pw = (char*)&Ps[w * 16 * 64];
  const int xc = (cc & 7) << 4;
  const int b = bh >> 4, h = bh & (NH - 1);

  auto stageKV = [&](int buf, int t) {
    const int kv0 = t * 64;
#pragma unroll
    for (int ch = 0; ch < 2; ++ch) {
      int R = sr + ch * 32;
      int dcol = (pb ^ ((R & 7) << 4)) >> 1;  // pre-swizzled global source
      async16((char*)Ks[buf] + ch * 4096 + w * 1024,
              Kb + ((size_t)bh * LSEQ + kv0 + R) * HDIM + dcol);
      async16((char*)Vs[buf] + ch * 4096 + w * 1024,
              Vt + ((size_t)bh * HDIM + R) * LSEQ + kv0 + dcol);
    }
  };

  const u16* Qg = Q + ((size_t)bh * LSEQ + q0 + w * 16) * HDIM;
  bf16x8 qf0 = *(const bf16x8*)&Qg[cc * HDIM + g * 8];
  bf16x8 qf1 = *(const bf16x8*)&Qg[cc * HDIM + 32 + g * 8];

  bf16x8 onesf;
#pragma unroll
  for (int z = 0; z < 8; ++z) onesf[z] = (__bf16)1.0f;

  f32x4 o[4] = {};
  f32x4 ls = {};
  float mrow[4];
#pragma unroll
  for (int r = 0; r < 4; ++r) mrow[r] = -3e38f;

  stageKV(0, 0);

  for (int t = 0; t < nt; ++t) {
    const int cur = t & 1;
    // issue next-tile prefetch, then wait ONLY for this tile's 4 loads
    if (t + 1 < nt) {
      stageKV(cur ^ 1, t + 1);
      asm volatile("s_waitcnt vmcnt(4)" ::: "memory");
    } else {
      asm volatile("s_waitcnt vmcnt(0)" ::: "memory");
    }
    __builtin_amdgcn_s_barrier();          // tile-t data visible to all waves
    __builtin_amdgcn_sched_barrier(0);
    const char* KsB = (const char*)Ks[cur];
    const char* VsB = (const char*)Vs[cur];

    // S = Q K^T (base-2 scaled); C: row=q (g*4+r), col=kv (cc) per nf-frag
    f32x4 sf[4] = {};
    __builtin_amdgcn_s_setprio(1);
#pragma unroll
    for (int nf = 0; nf < 4; ++nf) {
      bf16x8 kf0 = *(const bf16x8*)(KsB + (nf * 16 + cc) * 128 + ((g * 16) ^ xc));
      bf16x8 kf1 = *(const bf16x8*)(KsB + (nf * 16 + cc) * 128 + ((64 + g * 16) ^ xc));
      sf[nf] = mfma16(qf0, kf0, sf[nf]);
      sf[nf] = mfma16(qf1, kf1, sf[nf]);
    }
    __builtin_amdgcn_s_setprio(0);

    if (t == nt - 1) {  // diagonal tile: causal mask
#pragma unroll
      for (int nf = 0; nf < 4; ++nf) {
        int kvl = nf * 16 + cc;
#pragma unroll
        for (int r = 0; r < 4; ++r)
          if (kvl > w * 16 + g * 4 + r) sf[nf][r] = -1e30f;
      }
    }

    // tile max per row (4 shfl hops over the 16 lanes of group g)
    float tm[4];
#pragma unroll
    for (int r = 0; r < 4; ++r) {
      float m2 = fmaxf(fmaxf(sf[0][r], sf[1][r]), fmaxf(sf[2][r], sf[3][r]));
      m2 = fmaxf(m2, __shfl_xor(m2, 1));
      m2 = fmaxf(m2, __shfl_xor(m2, 2));
      m2 = fmaxf(m2, __shfl_xor(m2, 4));
      m2 = fmaxf(m2, __shfl_xor(m2, 8));
      tm[r] = m2;
    }
    // defer-rescale (T13): only rescale when max grew by > 8 (base-2)
    float dmax = fmaxf(fmaxf(tm[0] - mrow[0], tm[1] - mrow[1]),
                       fmaxf(tm[2] - mrow[2], tm[3] - mrow[3]));
    if (__any(dmax > 8.f)) {
#pragma unroll
      for (int r = 0; r < 4; ++r) {
        float mnew = fmaxf(mrow[r], tm[r]);
        float sc = EXP2(mrow[r] - mnew);
        mrow[r] = mnew;
        ls[r] *= sc;
#pragma unroll
        for (int nf = 0; nf < 4; ++nf) o[nf][r] *= sc;
      }
    }

    // P = exp2(S - m), write to per-wave LDS (swizzled); same-wave dep
#pragma unroll
    for (int r = 0; r < 4; ++r) {
      int q = g * 4 + r;
      int xr = (q & 7) << 4;
#pragma unroll
      for (int nf = 0; nf < 4; ++nf) {
        float pv = EXP2(sf[nf][r] - mrow[r]);
        *(u16*)(Pw + q * 128 + (((nf * 16 + cc) * 2) ^ xr)) = cvt_bf(pv);
      }
    }
    asm volatile("s_waitcnt lgkmcnt(0)" ::: "memory");
    __builtin_amdgcn_sched_barrier(0);

    bf16x8 pf0 = *(const bf16x8*)(Pw + cc * 128 + ((g * 16) ^ xc));
    bf16x8 pf1 = *(const bf16x8*)(Pw + cc * 128 + ((64 + g * 16) ^ xc));
    __builtin_amdgcn_s_setprio(1);
    // row-sum of P via MFMA against all-ones (replaces shfl-add reduce)
    ls = mfma16(pf1, onesf, mfma16(pf0, onesf, ls));
#pragma unroll
    for (int nf = 0; nf < 4; ++nf) {
      bf16x8 vf0 = *(const bf16x8*)(VsB + (nf * 16 + cc) * 128 + ((g * 16) ^ xc));
      bf16x8 vf1 = *(const bf16x8*)(VsB + (nf * 16 + cc) * 128 + ((64 + g * 16) ^ xc));
      o[nf] = mfma16(pf0, vf0, o[nf]);
      o[nf] = mfma16(pf1, vf1, o[nf]);
    }
    __builtin_amdgcn_s_setprio(0);
    // WAR guard: all waves done reading buffer `cur` before it is re-staged
    // next iteration. Raw barrier -- no vmcnt drain (prefetch stays in flight).
    __builtin_amdgcn_s_barrier();
  }

  // epilogue: Y[b, q, h*64 + d]
#pragma unroll
  for (int r = 0; r < 4; ++r) {
    float inv = 1.0f / ls[r];
    int row = q0 + w * 16 + g * 4 + r;
    size_t base = ((size_t)b * LSEQ + row) * EMB + h * HDIM;
#pragma unroll
    for (int nf = 0; nf < 4; ++nf)
      Y[base + nf * 16 + cc] = cvt_bf(o[nf][r] * inv);
  }
}

// ---------------- mean-V fixup for rows >= mask_len ----------------
__global__ void meanv_fill(const u16* __restrict__ Vt, const int* __restrict__ mask_len,
                           u16* __restrict__ Y) {
  __shared__ float partial[256];
  __shared__ u16 mv[HDIM];
  int bh = blockIdx.x, b = bh >> 4, h = bh & (NH - 1);
  int tid = threadIdx.x;
  int d = tid >> 2, part = tid & 3;
  const u16* src = Vt + ((size_t)bh * HDIM + d) * LSEQ + part * 512;
  float s = 0.f;
  for (int i = 0; i < 512; i += 8) {
    u16x8 v = *(const u16x8*)&src[i];
#pragma unroll
    for (int j = 0; j < 8; ++j) s += bf2f(v[j]);
  }
  partial[tid] = s;
  __syncthreads();
  if (part == 0) {
    float t = partial[tid] + partial[tid + 1] + partial[tid + 2] + partial[tid + 3];
    mv[d] = cvt_bf(t * (1.0f / (float)LSEQ));
  }
  __syncthreads();
  int lo = mask_len[b];
  if (lo < 0) lo = 0;
  if (lo > LSEQ) lo = LSEQ;
  int total = (LSEQ - lo) * HDIM;
  for (int idx = tid; idx < total; idx += 256) {
    int row = lo + (idx >> 6), dd = idx & 63;
    Y[((size_t)b * LSEQ + row) * EMB + h * HDIM + dd] = mv[dd];
  }
}

// ---------------- launch ----------------
extern "C" void kernel_launch(void* const* d_in, const int* in_sizes, int n_in,
                              void* d_out, int out_size, void* d_ws, size_t ws_size,
                              hipStream_t stream) {
  (void)in_sizes; (void)n_in; (void)out_size; (void)ws_size;
  const float* x    = (const float*)d_in[0];
  const float* Wqkv = (const float*)d_in[1];
  const float* bqkv = (const float*)d_in[2];
  const float* Wo   = (const float*)d_in[3];
  const float* bo   = (const float*)d_in[4];
  const int* mask_len = (const int*)d_in[5];
  float* out = (float*)d_out;

  u16* ws = (u16*)d_ws;
  u16* xb    = ws;                              // 4M elems (x bf16) — reused as Y later
  u16* wqkvt = ws + (size_t)4 * 1024 * 1024;    // 3M (W_qkv^T bf16)
  u16* wot   = wqkvt + (size_t)3 * 1024 * 1024; // 1M (W_o^T bf16)
  u16* Qb    = wot + (size_t)1024 * 1024;       // 4M
  u16* Kb    = Qb + (size_t)4 * 1024 * 1024;    // 4M
  u16* Vtb   = Kb + (size_t)4 * 1024 * 1024;    // 4M
  u16* Yb    = xb;                              // alias: x dead after gemm_qkv

  f32_to_bf16_vec<<<4096, 256, 0, stream>>>(x, xb, 1024 * 1024);
  dim3 tb(32, 8);
  transpose_f32_bf16<<<dim3(96, 32), tb, 0, stream>>>(Wqkv, wqkvt, 1024, 3072);
  transpose_f32_bf16<<<dim3(32, 32), tb, 0, stream>>>(Wo, wot, 1024, 1024);
  gemm_bt<3072, 0><<<dim3(24, 32), 256, 0, stream>>>(xb, wqkvt, bqkv, nullptr, Qb, Kb, Vtb);
  attn_fwd<<<1024, 256, 0, stream>>>(Qb, Kb, Vtb, Yb);
  meanv_fill<<<32, 256, 0, stream>>>(Vtb, mask_len, Yb);
  gemm_bt<1024, 1><<<dim3(8, 32), 256, 0, stream>>>(Yb, wot, bo, out, nullptr, nullptr, nullptr);
}